// Round 1
// baseline (390.204 us; speedup 1.0000x reference)
//
#include <hip/hip_runtime.h>

#define GRAVITY_F 9.81f
#define EPT 4  // elements per thread

typedef int   v4i __attribute__((ext_vector_type(4)));
// Honest 4-byte alignment: pos gathers are at byte offset 12*idx. With
// unaligned-access-mode (default on gfx9xx) this still emits one
// global_load_dwordx4; if the backend ever disallows it, it legally splits.
typedef float v4f __attribute__((ext_vector_type(4), aligned(4)));

__device__ __forceinline__ float blockReduceSum(float val) {
    #pragma unroll
    for (int off = 32; off > 0; off >>= 1)
        val += __shfl_down(val, off, 64);
    __shared__ float smem[16];
    const int lane = threadIdx.x & 63;
    const int wave = threadIdx.x >> 6;
    if (lane == 0) smem[wave] = val;
    __syncthreads();
    const int nwaves = (blockDim.x + 63) >> 6;
    val = 0.0f;
    if (wave == 0) {
        if (lane < nwaves) val = smem[lane];
        #pragma unroll
        for (int off = 8; off > 0; off >>= 1)
            val += __shfl_down(val, off, 64);
    }
    return val;  // valid on thread 0 only
}

// Blocks [0, Eblocks): element terms, EPT elems/thread.
// Blocks [Eblocks, ...): vertex terms, 1 vertex/thread (exact fp32).
// waves_per_eu(4,4): pin target occupancy at 4 waves/EU so the scheduler
// uses the full 128-VGPR budget and keeps all 16 gathers + 36 R loads in
// flight instead of register-minimizing down to 36 VGPRs (serialized MLP).
__global__ __launch_bounds__(256)
__attribute__((amdgpu_waves_per_eu(4, 4)))
void fused_kernel(const float* __restrict__ pn,
                  const float* __restrict__ pc,
                  const float* __restrict__ pp,
                  const float* __restrict__ mass,
                  const int*   __restrict__ elems,
                  const float* __restrict__ vols,
                  const float* __restrict__ rinv,
                  const float* __restrict__ lam_p,
                  const float* __restrict__ mu_p,
                  float* __restrict__ partials,
                  unsigned int* __restrict__ counter,  // null -> external reduce
                  float* __restrict__ out,
                  int V, int E, int Eblocks,
                  float sI, float sG, float sS) {
    float local = 0.0f;

    if ((int)blockIdx.x < Eblocks) {
        const float lam = lam_p[0];
        const float mu  = mu_p[0];
        const int base = blockIdx.x * (EPT * 256) + threadIdx.x;

        int   ec[EPT];
        float sc[EPT];
        #pragma unroll
        for (int i = 0; i < EPT; ++i) {
            const int e = base + i * 256;
            ec[i] = e < E ? e : (E - 1);
            sc[i] = e < E ? sS : 0.0f;
        }

        v4i   idx[EPT];
        float vol[EPT];
        #pragma unroll
        for (int i = 0; i < EPT; ++i) {
            idx[i] = __builtin_nontemporal_load(((const v4i*)elems) + ec[i]);
            vol[i] = __builtin_nontemporal_load(vols + ec[i]);
        }

        // 16 in-flight dwordx4 gathers: 12 used bytes + 4 slack per vertex.
        // Window clamped so the last vertex stays in-bounds; fixed up below
        // with 3 cndmasks. (48 divergent dword gathers -> 16 dwordx4.)
        const int cap = 3 * V - 4;
        v4f q[EPT][4];
        #pragma unroll
        for (int i = 0; i < EPT; ++i) {
            #pragma unroll
            for (int j = 0; j < 4; ++j) {
                int off = 3 * idx[i][j];
                off = off > cap ? cap : off;   // only triggers for idx == V-1
                q[i][j] = *reinterpret_cast<const v4f*>(pn + off);
            }
        }

        float R[EPT][9];
        #pragma unroll
        for (int i = 0; i < EPT; ++i) {
            const float* Rp = rinv + 9 * (size_t)ec[i];
            #pragma unroll
            for (int k = 0; k < 9; ++k)
                R[i][k] = __builtin_nontemporal_load(Rp + k);
        }

        const int lastV = V - 1;
        #pragma unroll
        for (int i = 0; i < EPT; ++i) {
            float x[4][3];
            #pragma unroll
            for (int j = 0; j < 4; ++j) {
                const bool sh = (idx[i][j] == lastV);
                x[j][0] = sh ? q[i][j][1] : q[i][j][0];
                x[j][1] = sh ? q[i][j][2] : q[i][j][1];
                x[j][2] = sh ? q[i][j][3] : q[i][j][2];
            }
            float d[3][3];
            #pragma unroll
            for (int r = 0; r < 3; ++r) {
                d[r][0] = x[1][r] - x[0][r];
                d[r][1] = x[2][r] - x[0][r];
                d[r][2] = x[3][r] - x[0][r];
            }
            float F[3][3];
            #pragma unroll
            for (int r = 0; r < 3; ++r)
                #pragma unroll
                for (int k = 0; k < 3; ++k)
                    F[r][k] = d[r][0] * R[i][0 * 3 + k]
                            + d[r][1] * R[i][1 * 3 + k]
                            + d[r][2] * R[i][2 * 3 + k];
            const float det = F[0][0] * (F[1][1] * F[2][2] - F[1][2] * F[2][1])
                            - F[0][1] * (F[1][0] * F[2][2] - F[1][2] * F[2][0])
                            + F[0][2] * (F[1][0] * F[2][1] - F[1][1] * F[2][0]);
            const float ld = logf(fmaxf(det, 1e-8f));
            float tr = 0.0f;
            #pragma unroll
            for (int r = 0; r < 3; ++r)
                #pragma unroll
                for (int k = 0; k < 3; ++k)
                    tr += F[r][k] * F[r][k];
            const float psi = 0.5f * lam * ld * ld - mu * ld + 0.5f * mu * (tr - 3.0f);
            local += sc[i] * (psi * vol[i]);
        }
    } else {
        const int v = (blockIdx.x - Eblocks) * blockDim.x + threadIdx.x;
        if (v < V) {
            const float m  = __builtin_nontemporal_load(mass + v);
            const float p0 = __builtin_nontemporal_load(pc + 3 * v + 0);
            const float y  = __builtin_nontemporal_load(pc + 3 * v + 1);
            const float p2 = __builtin_nontemporal_load(pc + 3 * v + 2);
            const float n0 = __builtin_nontemporal_load(pn + 3 * v + 0);
            const float n1 = __builtin_nontemporal_load(pn + 3 * v + 1);
            const float n2 = __builtin_nontemporal_load(pn + 3 * v + 2);
            const float q0 = __builtin_nontemporal_load(pp + 3 * v + 0);
            const float q1 = __builtin_nontemporal_load(pp + 3 * v + 1);
            const float q2 = __builtin_nontemporal_load(pp + 3 * v + 2);
            const float a0 = n0 + q0 - 2.0f * p0;
            const float a1 = n1 + q1 - 2.0f * y;
            const float a2 = n2 + q2 - 2.0f * p2;
            local = sI * (m * (a0 * a0 + a1 * a1 + a2 * a2)) + sG * (m * y);
        }
    }

    const float tot = blockReduceSum(local);

    // Ticket-based last-block reduction (replaces the reduce_kernel
    // dispatch). Numerics are bitwise-identical to the old two-pass flow:
    // same float partials, same double strided-sum + tree.
    __shared__ bool isLast;
    if (threadIdx.x == 0) {
        partials[blockIdx.x] = tot;
        bool last = false;
        if (counter) {
            __threadfence();  // make our partial visible device-wide
            const unsigned t = atomicAdd(counter, 1u);
            last = (t == gridDim.x - 1);
        }
        isLast = last;
    }
    __syncthreads();
    if (isLast) {
        __threadfence();  // acquire: invalidate stale L1/L2 lines
        double s = 0.0;
        const int n = (int)gridDim.x;
        for (int i = threadIdx.x; i < n; i += blockDim.x)
            s += (double)partials[i];
        __shared__ double sm[256];
        sm[threadIdx.x] = s;
        __syncthreads();
        #pragma unroll
        for (int off = 128; off > 0; off >>= 1) {
            if (threadIdx.x < off) sm[threadIdx.x] += sm[threadIdx.x + off];
            __syncthreads();
        }
        if (threadIdx.x == 0) out[0] = (float)sm[0];
    }
}

// Fallback only (ws too small for header + partials): old two-pass reduce.
__global__ void reduce_kernel(const float* __restrict__ partials, int n,
                              float* __restrict__ out) {
    double s = 0.0;
    for (int i = threadIdx.x; i < n; i += blockDim.x)
        s += (double)partials[i];
    __shared__ double sm[256];
    sm[threadIdx.x] = s;
    __syncthreads();
    #pragma unroll
    for (int off = 128; off > 0; off >>= 1) {
        if (threadIdx.x < off) sm[threadIdx.x] += sm[threadIdx.x + off];
        __syncthreads();
    }
    if (threadIdx.x == 0) out[0] = (float)sm[0];
}

extern "C" void kernel_launch(void* const* d_in, const int* in_sizes, int n_in,
                              void* d_out, int out_size, void* d_ws, size_t ws_size,
                              hipStream_t stream) {
    const float* pos_next = (const float*)d_in[0];
    const float* pos_curr = (const float*)d_in[1];
    const float* pos_prev = (const float*)d_in[2];
    const float* mass     = (const float*)d_in[3];
    const int*   elements = (const int*)d_in[4];
    const float* rest_vol = (const float*)d_in[5];
    const float* rest_inv = (const float*)d_in[6];
    const float* lam_p    = (const float*)d_in[7];
    const float* mu_p     = (const float*)d_in[8];
    float* out = (float*)d_out;

    const int V = in_sizes[3];  // mass has V elements
    const int E = in_sizes[5];  // rest_volumes has E elements

    const float sI = 0.5f / (3.0f * (float)V);       // W_INERTIA * 0.5 / (3V)
    const float sG = -0.01f * GRAVITY_F / (float)V;  // W_GRAVITY * (-g) / V
    const float sS = 1.0f / (float)E;                // W_STRAIN / E

    const int block = 256;
    const int Eblocks = (E + EPT * block - 1) / (EPT * block);
    const int Vblocks = (V + block - 1) / block;
    const int grid = Eblocks + Vblocks;

    unsigned int* counter = (unsigned int*)d_ws;                 // 4 B @ offset 0
    float* partials = (float*)((char*)d_ws + 256);               // grid floats
    const size_t need = 256 + (size_t)grid * sizeof(float);

    if (ws_size >= need) {
        hipMemsetAsync(d_ws, 0, 4, stream);  // zero the ticket counter
        fused_kernel<<<grid, block, 0, stream>>>(pos_next, pos_curr, pos_prev,
                                                 mass, elements, rest_vol,
                                                 rest_inv, lam_p, mu_p,
                                                 partials, counter, out,
                                                 V, E, Eblocks, sI, sG, sS);
    } else {
        float* p2 = (float*)d_ws;
        fused_kernel<<<grid, block, 0, stream>>>(pos_next, pos_curr, pos_prev,
                                                 mass, elements, rest_vol,
                                                 rest_inv, lam_p, mu_p,
                                                 p2, nullptr, out,
                                                 V, E, Eblocks, sI, sG, sS);
        reduce_kernel<<<1, 256, 0, stream>>>(p2, grid, out);
    }
}

// Round 2
// 218.599 us; speedup vs baseline: 1.7850x; 1.7850x over previous
//
#include <hip/hip_runtime.h>

#define GRAVITY_F 9.81f
#define EPT 2  // elements per thread (keeps forced-live set under the 128-VGPR cap)

typedef int   v4i __attribute__((ext_vector_type(4)));
// 4-byte-aligned float4: pos gathers sit at byte offset 12*idx. gfx950 global
// loads support unaligned dwordx4 in hardware.
typedef float v4f __attribute__((ext_vector_type(4), aligned(4)));

__device__ __forceinline__ float blockReduceSum(float val) {
    #pragma unroll
    for (int off = 32; off > 0; off >>= 1)
        val += __shfl_down(val, off, 64);
    __shared__ float smem[16];
    const int lane = threadIdx.x & 63;
    const int wave = threadIdx.x >> 6;
    if (lane == 0) smem[wave] = val;
    __syncthreads();
    const int nwaves = (blockDim.x + 63) >> 6;
    val = 0.0f;
    if (wave == 0) {
        if (lane < nwaves) val = smem[lane];
        #pragma unroll
        for (int off = 8; off > 0; off >>= 1)
            val += __shfl_down(val, off, 64);
    }
    return val;  // valid on thread 0 only
}

// Blocks [0, Eblocks): element terms, EPT elems/thread.
// Blocks [Eblocks, ...): vertex terms, 1 vertex/thread (exact fp32).
// NO device-scope fences anywhere in this kernel: __threadfence() on gfx950
// writes back / invalidates the per-XCD L2 and evicted the gather table in
// round 1 (+122 MB HBM fetch). Reduction stays two-pass.
__global__ void __launch_bounds__(256, 4)
fused_kernel(const float* __restrict__ pn,
             const float* __restrict__ pc,
             const float* __restrict__ pp,
             const float* __restrict__ mass,
             const int*   __restrict__ elems,
             const float* __restrict__ vols,
             const float* __restrict__ rinv,
             const float* __restrict__ lam_p,
             const float* __restrict__ mu_p,
             float* __restrict__ partials,
             int V, int E, int Eblocks,
             float sI, float sG, float sS) {
    float local = 0.0f;

    if ((int)blockIdx.x < Eblocks) {
        const float lam = lam_p[0];
        const float mu  = mu_p[0];
        const int base = blockIdx.x * (EPT * 256) + threadIdx.x;

        int   ec[EPT];
        float sc[EPT];
        #pragma unroll
        for (int i = 0; i < EPT; ++i) {
            const int e = base + i * 256;
            ec[i] = e < E ? e : (E - 1);
            sc[i] = e < E ? sS : 0.0f;
        }

        // --- issue ALL loads as one cluster -------------------------------
        // 1) element indices (oldest in the vmcnt queue; the gather address
        //    calc only needs these two to retire)
        v4i idx[EPT];
        #pragma unroll
        for (int i = 0; i < EPT; ++i)
            idx[i] = __builtin_nontemporal_load(((const v4i*)elems) + ec[i]);

        // 2) rinv as dwordx4 + dwordx4 + dword (36 B/elem: 9 scalar -> 3 vec)
        v4f rA[EPT], rB[EPT];
        float rC[EPT], vol[EPT];
        #pragma unroll
        for (int i = 0; i < EPT; ++i) {
            const float* Rp = rinv + 9 * (size_t)ec[i];
            rA[i]  = __builtin_nontemporal_load((const v4f*)Rp);
            rB[i]  = __builtin_nontemporal_load((const v4f*)(Rp + 4));
            rC[i]  = __builtin_nontemporal_load(Rp + 8);
            vol[i] = __builtin_nontemporal_load(vols + ec[i]);
        }

        // 3) vertex gathers: one unaligned dwordx4 per vertex (12 used bytes
        //    + 4 slack). Window clamped at the buffer end; fixed up with
        //    cndmasks below. 48 divergent dwords -> 8 dwordx4.
        const int cap = 3 * V - 4;
        v4f q[EPT][4];
        #pragma unroll
        for (int i = 0; i < EPT; ++i) {
            #pragma unroll
            for (int j = 0; j < 4; ++j) {
                int off = 3 * idx[i][j];
                off = off > cap ? cap : off;   // only triggers for idx == V-1
                q[i][j] = *reinterpret_cast<const v4f*>(pn + off);
            }
        }

        // Force every load result live at this point: prevents the scheduler
        // from register-minimizing (round 0: 36 VGPRs, fully serialized
        // gathers). All 16 VMEM loads stay in flight together.
        asm volatile("" ::
            "v"(q[0][0]), "v"(q[0][1]), "v"(q[0][2]), "v"(q[0][3]),
            "v"(q[1][0]), "v"(q[1][1]), "v"(q[1][2]), "v"(q[1][3]),
            "v"(rA[0]), "v"(rB[0]), "v"(rA[1]), "v"(rB[1]),
            "v"(rC[0]), "v"(rC[1]), "v"(vol[0]), "v"(vol[1]));

        const int lastV = V - 1;
        #pragma unroll
        for (int i = 0; i < EPT; ++i) {
            float x[4][3];
            #pragma unroll
            for (int j = 0; j < 4; ++j) {
                const bool sh = (idx[i][j] == lastV);
                x[j][0] = sh ? q[i][j][1] : q[i][j][0];
                x[j][1] = sh ? q[i][j][2] : q[i][j][1];
                x[j][2] = sh ? q[i][j][3] : q[i][j][2];
            }
            const float R[9] = { rA[i][0], rA[i][1], rA[i][2], rA[i][3],
                                 rB[i][0], rB[i][1], rB[i][2], rB[i][3],
                                 rC[i] };
            float d[3][3];
            #pragma unroll
            for (int r = 0; r < 3; ++r) {
                d[r][0] = x[1][r] - x[0][r];
                d[r][1] = x[2][r] - x[0][r];
                d[r][2] = x[3][r] - x[0][r];
            }
            float F[3][3];
            #pragma unroll
            for (int r = 0; r < 3; ++r)
                #pragma unroll
                for (int k = 0; k < 3; ++k)
                    F[r][k] = d[r][0] * R[0 * 3 + k]
                            + d[r][1] * R[1 * 3 + k]
                            + d[r][2] * R[2 * 3 + k];
            const float det = F[0][0] * (F[1][1] * F[2][2] - F[1][2] * F[2][1])
                            - F[0][1] * (F[1][0] * F[2][2] - F[1][2] * F[2][0])
                            + F[0][2] * (F[1][0] * F[2][1] - F[1][1] * F[2][0]);
            const float ld = logf(fmaxf(det, 1e-8f));
            float tr = 0.0f;
            #pragma unroll
            for (int r = 0; r < 3; ++r)
                #pragma unroll
                for (int k = 0; k < 3; ++k)
                    tr += F[r][k] * F[r][k];
            const float psi = 0.5f * lam * ld * ld - mu * ld + 0.5f * mu * (tr - 3.0f);
            local += sc[i] * (psi * vol[i]);
        }
    } else {
        const int v = (blockIdx.x - Eblocks) * blockDim.x + threadIdx.x;
        if (v < V) {
            const float m  = __builtin_nontemporal_load(mass + v);
            const float p0 = __builtin_nontemporal_load(pc + 3 * v + 0);
            const float y  = __builtin_nontemporal_load(pc + 3 * v + 1);
            const float p2 = __builtin_nontemporal_load(pc + 3 * v + 2);
            const float n0 = __builtin_nontemporal_load(pn + 3 * v + 0);
            const float n1 = __builtin_nontemporal_load(pn + 3 * v + 1);
            const float n2 = __builtin_nontemporal_load(pn + 3 * v + 2);
            const float q0 = __builtin_nontemporal_load(pp + 3 * v + 0);
            const float q1 = __builtin_nontemporal_load(pp + 3 * v + 1);
            const float q2 = __builtin_nontemporal_load(pp + 3 * v + 2);
            const float a0 = n0 + q0 - 2.0f * p0;
            const float a1 = n1 + q1 - 2.0f * y;
            const float a2 = n2 + q2 - 2.0f * p2;
            local = sI * (m * (a0 * a0 + a1 * a1 + a2 * a2)) + sG * (m * y);
        }
    }

    const float tot = blockReduceSum(local);
    if (threadIdx.x == 0) partials[blockIdx.x] = tot;
}

__global__ void reduce_kernel(const float* __restrict__ partials, int n,
                              float* __restrict__ out) {
    double s = 0.0;
    for (int i = threadIdx.x; i < n; i += blockDim.x)
        s += (double)partials[i];
    __shared__ double sm[256];
    sm[threadIdx.x] = s;
    __syncthreads();
    #pragma unroll
    for (int off = 128; off > 0; off >>= 1) {
        if (threadIdx.x < off) sm[threadIdx.x] += sm[threadIdx.x + off];
        __syncthreads();
    }
    if (threadIdx.x == 0) out[0] = (float)sm[0];
}

extern "C" void kernel_launch(void* const* d_in, const int* in_sizes, int n_in,
                              void* d_out, int out_size, void* d_ws, size_t ws_size,
                              hipStream_t stream) {
    const float* pos_next = (const float*)d_in[0];
    const float* pos_curr = (const float*)d_in[1];
    const float* pos_prev = (const float*)d_in[2];
    const float* mass     = (const float*)d_in[3];
    const int*   elements = (const int*)d_in[4];
    const float* rest_vol = (const float*)d_in[5];
    const float* rest_inv = (const float*)d_in[6];
    const float* lam_p    = (const float*)d_in[7];
    const float* mu_p     = (const float*)d_in[8];
    float* out = (float*)d_out;

    const int V = in_sizes[3];  // mass has V elements
    const int E = in_sizes[5];  // rest_volumes has E elements

    const float sI = 0.5f / (3.0f * (float)V);       // W_INERTIA * 0.5 / (3V)
    const float sG = -0.01f * GRAVITY_F / (float)V;  // W_GRAVITY * (-g) / V
    const float sS = 1.0f / (float)E;                // W_STRAIN / E

    const int block = 256;
    const int Eblocks = (E + EPT * block - 1) / (EPT * block);
    const int Vblocks = (V + block - 1) / block;
    const int grid = Eblocks + Vblocks;

    float* partials = (float*)d_ws;  // grid floats; every slot overwritten

    fused_kernel<<<grid, block, 0, stream>>>(pos_next, pos_curr, pos_prev,
                                             mass, elements, rest_vol,
                                             rest_inv, lam_p, mu_p,
                                             partials, V, E, Eblocks,
                                             sI, sG, sS);
    reduce_kernel<<<1, 256, 0, stream>>>(partials, grid, out);
}

// Round 3
// 217.902 us; speedup vs baseline: 1.7907x; 1.0032x over previous
//
#include <hip/hip_runtime.h>

#define GRAVITY_F 9.81f
#define EPT 2  // elements per thread

typedef int   v4i  __attribute__((ext_vector_type(4)));
typedef float v4f  __attribute__((ext_vector_type(4), aligned(16)));  // truly aligned
typedef float v4fu __attribute__((ext_vector_type(4), aligned(4)));   // rinv (36B stride)

__device__ __forceinline__ float blockReduceSum(float val) {
    #pragma unroll
    for (int off = 32; off > 0; off >>= 1)
        val += __shfl_down(val, off, 64);
    __shared__ float smem[16];
    const int lane = threadIdx.x & 63;
    const int wave = threadIdx.x >> 6;
    if (lane == 0) smem[wave] = val;
    __syncthreads();
    const int nwaves = (blockDim.x + 63) >> 6;
    val = 0.0f;
    if (wave == 0) {
        if (lane < nwaves) val = smem[lane];
        #pragma unroll
        for (int off = 8; off > 0; off >>= 1)
            val += __shfl_down(val, off, 64);
    }
    return val;  // valid on thread 0 only
}

// Grid layout: blocks [0, Vblocks4) = vertex terms FIRST (4 verts/thread,
// aligned dwordx4 streams; pn loads are TEMPORAL to pre-warm L2/L3 with the
// gather table). Blocks [Vblocks4, ...) = element terms, EPT elems/thread,
// gathers as 3 scalar cached dwords per vertex (round-0-proven: absorbed by
// L2/L3, FETCH stays at ideal; unaligned dwordx4 gathers cost +117 MB HBM).
__global__ void __launch_bounds__(256, 4)
fused_kernel(const float* __restrict__ pn,
             const float* __restrict__ pc,
             const float* __restrict__ pp,
             const float* __restrict__ mass,
             const int*   __restrict__ elems,
             const float* __restrict__ vols,
             const float* __restrict__ rinv,
             const float* __restrict__ lam_p,
             const float* __restrict__ mu_p,
             float* __restrict__ partials,
             int V, int E, int Vblocks4,
             float sI, float sG, float sS) {
    float local = 0.0f;

    if ((int)blockIdx.x >= Vblocks4) {
        const float lam = lam_p[0];
        const float mu  = mu_p[0];
        const int eb   = blockIdx.x - Vblocks4;
        const int base = eb * (EPT * 256) + threadIdx.x;

        int   ec[EPT];
        float sc[EPT];
        #pragma unroll
        for (int i = 0; i < EPT; ++i) {
            const int e = base + i * 256;
            ec[i] = e < E ? e : (E - 1);
            sc[i] = e < E ? sS : 0.0f;
        }

        // ---- one load cluster: idx first (retires early), then rinv/vol
        //      streams, then the 24 cached gather dwords -------------------
        v4i idx[EPT];
        #pragma unroll
        for (int i = 0; i < EPT; ++i)
            idx[i] = __builtin_nontemporal_load(((const v4i*)elems) + ec[i]);

        v4fu rA[EPT], rB[EPT];
        float rC[EPT], vol[EPT];
        #pragma unroll
        for (int i = 0; i < EPT; ++i) {
            const float* Rp = rinv + 9 * (size_t)ec[i];
            rA[i]  = __builtin_nontemporal_load((const v4fu*)Rp);
            rB[i]  = __builtin_nontemporal_load((const v4fu*)(Rp + 4));
            rC[i]  = __builtin_nontemporal_load(Rp + 8);
            vol[i] = __builtin_nontemporal_load(vols + ec[i]);
        }

        // Gathers: EXACT round-0 code shape (proven cache-friendly codegen).
        float x[EPT][4][3];
        #pragma unroll
        for (int i = 0; i < EPT; ++i) {
            const float* v0 = pn + 3 * (size_t)idx[i].x;
            const float* v1 = pn + 3 * (size_t)idx[i].y;
            const float* v2 = pn + 3 * (size_t)idx[i].z;
            const float* v3 = pn + 3 * (size_t)idx[i].w;
            #pragma unroll
            for (int r = 0; r < 3; ++r) {
                x[i][0][r] = v0[r];
                x[i][1][r] = v1[r];
                x[i][2][r] = v2[r];
                x[i][3][r] = v3[r];
            }
        }

        // Pin all load results live at one point so the scheduler keeps the
        // whole cluster in flight (round 0 register-minimized to 36 VGPRs and
        // serialized the gathers; round 2 proved this fixes the rate).
        asm volatile("" ::
            "v"(x[0][0][0]), "v"(x[0][0][1]), "v"(x[0][0][2]),
            "v"(x[0][1][0]), "v"(x[0][1][1]), "v"(x[0][1][2]),
            "v"(x[0][2][0]), "v"(x[0][2][1]), "v"(x[0][2][2]),
            "v"(x[0][3][0]), "v"(x[0][3][1]), "v"(x[0][3][2]),
            "v"(x[1][0][0]), "v"(x[1][0][1]), "v"(x[1][0][2]),
            "v"(x[1][1][0]), "v"(x[1][1][1]), "v"(x[1][1][2]),
            "v"(x[1][2][0]), "v"(x[1][2][1]), "v"(x[1][2][2]),
            "v"(x[1][3][0]), "v"(x[1][3][1]), "v"(x[1][3][2]),
            "v"(rA[0]), "v"(rB[0]), "v"(rA[1]), "v"(rB[1]),
            "v"(rC[0]), "v"(rC[1]), "v"(vol[0]), "v"(vol[1]));

        #pragma unroll
        for (int i = 0; i < EPT; ++i) {
            const float R[9] = { rA[i][0], rA[i][1], rA[i][2], rA[i][3],
                                 rB[i][0], rB[i][1], rB[i][2], rB[i][3],
                                 rC[i] };
            float d[3][3];
            #pragma unroll
            for (int r = 0; r < 3; ++r) {
                d[r][0] = x[i][1][r] - x[i][0][r];
                d[r][1] = x[i][2][r] - x[i][0][r];
                d[r][2] = x[i][3][r] - x[i][0][r];
            }
            float F[3][3];
            #pragma unroll
            for (int r = 0; r < 3; ++r)
                #pragma unroll
                for (int k = 0; k < 3; ++k)
                    F[r][k] = d[r][0] * R[0 * 3 + k]
                            + d[r][1] * R[1 * 3 + k]
                            + d[r][2] * R[2 * 3 + k];
            const float det = F[0][0] * (F[1][1] * F[2][2] - F[1][2] * F[2][1])
                            - F[0][1] * (F[1][0] * F[2][2] - F[1][2] * F[2][0])
                            + F[0][2] * (F[1][0] * F[2][1] - F[1][1] * F[2][0]);
            const float ld = logf(fmaxf(det, 1e-8f));
            float tr = 0.0f;
            #pragma unroll
            for (int r = 0; r < 3; ++r)
                #pragma unroll
                for (int k = 0; k < 3; ++k)
                    tr += F[r][k] * F[r][k];
            const float psi = 0.5f * lam * ld * ld - mu * ld + 0.5f * mu * (tr - 3.0f);
            local += sc[i] * (psi * vol[i]);
        }
    } else {
        // Vertex path: 4 vertices per thread. All vector loads 16B-aligned
        // (byte offsets 16g / 48g). pn loads TEMPORAL (warm the gather table);
        // pc/pp/mass nontemporal (single use).
        const int g  = blockIdx.x * blockDim.x + threadIdx.x;
        const int v0 = g * 4;
        if (v0 + 4 <= V) {
            const v4f m4 = *(const v4f*)(mass + v0);
            const v4f n0 = *(const v4f*)(pn + 3 * v0);
            const v4f n1 = *(const v4f*)(pn + 3 * v0 + 4);
            const v4f n2 = *(const v4f*)(pn + 3 * v0 + 8);
            const v4f c0 = __builtin_nontemporal_load((const v4f*)(pc + 3 * v0));
            const v4f c1 = __builtin_nontemporal_load((const v4f*)(pc + 3 * v0 + 4));
            const v4f c2 = __builtin_nontemporal_load((const v4f*)(pc + 3 * v0 + 8));
            const v4f q0 = __builtin_nontemporal_load((const v4f*)(pp + 3 * v0));
            const v4f q1 = __builtin_nontemporal_load((const v4f*)(pp + 3 * v0 + 4));
            const v4f q2 = __builtin_nontemporal_load((const v4f*)(pp + 3 * v0 + 8));
            const v4f N[3] = { n0, n1, n2 };
            const v4f C[3] = { c0, c1, c2 };
            const v4f Q[3] = { q0, q1, q2 };
            #pragma unroll
            for (int i = 0; i < 4; ++i) {
                float acc = 0.0f;
                #pragma unroll
                for (int r = 0; r < 3; ++r) {
                    const int k = 3 * i + r;
                    const float a = N[k >> 2][k & 3] + Q[k >> 2][k & 3]
                                  - 2.0f * C[k >> 2][k & 3];
                    acc += a * a;
                }
                const int ky = 3 * i + 1;
                const float y = C[ky >> 2][ky & 3];
                local += sI * (m4[i] * acc) + sG * (m4[i] * y);
            }
        } else {
            for (int v = v0; v < V; ++v) {
                const float m  = mass[v];
                const float p0 = pc[3 * v + 0];
                const float y  = pc[3 * v + 1];
                const float p2 = pc[3 * v + 2];
                const float a0 = pn[3 * v + 0] + pp[3 * v + 0] - 2.0f * p0;
                const float a1 = pn[3 * v + 1] + pp[3 * v + 1] - 2.0f * y;
                const float a2 = pn[3 * v + 2] + pp[3 * v + 2] - 2.0f * p2;
                local += sI * (m * (a0 * a0 + a1 * a1 + a2 * a2)) + sG * (m * y);
            }
        }
    }

    const float tot = blockReduceSum(local);
    if (threadIdx.x == 0) partials[blockIdx.x] = tot;
}

__global__ void reduce_kernel(const float* __restrict__ partials, int n,
                              float* __restrict__ out) {
    double s = 0.0;
    for (int i = threadIdx.x; i < n; i += blockDim.x)
        s += (double)partials[i];
    __shared__ double sm[256];
    sm[threadIdx.x] = s;
    __syncthreads();
    #pragma unroll
    for (int off = 128; off > 0; off >>= 1) {
        if (threadIdx.x < off) sm[threadIdx.x] += sm[threadIdx.x + off];
        __syncthreads();
    }
    if (threadIdx.x == 0) out[0] = (float)sm[0];
}

extern "C" void kernel_launch(void* const* d_in, const int* in_sizes, int n_in,
                              void* d_out, int out_size, void* d_ws, size_t ws_size,
                              hipStream_t stream) {
    const float* pos_next = (const float*)d_in[0];
    const float* pos_curr = (const float*)d_in[1];
    const float* pos_prev = (const float*)d_in[2];
    const float* mass     = (const float*)d_in[3];
    const int*   elements = (const int*)d_in[4];
    const float* rest_vol = (const float*)d_in[5];
    const float* rest_inv = (const float*)d_in[6];
    const float* lam_p    = (const float*)d_in[7];
    const float* mu_p     = (const float*)d_in[8];
    float* out = (float*)d_out;

    const int V = in_sizes[3];  // mass has V elements
    const int E = in_sizes[5];  // rest_volumes has E elements

    const float sI = 0.5f / (3.0f * (float)V);       // W_INERTIA * 0.5 / (3V)
    const float sG = -0.01f * GRAVITY_F / (float)V;  // W_GRAVITY * (-g) / V
    const float sS = 1.0f / (float)E;                // W_STRAIN / E

    const int block = 256;
    const int Eblocks  = (E + EPT * block - 1) / (EPT * block);
    const int Vgroups  = (V + 3) / 4;
    const int Vblocks4 = (Vgroups + block - 1) / block;
    const int grid = Vblocks4 + Eblocks;

    float* partials = (float*)d_ws;  // grid floats; every slot overwritten

    fused_kernel<<<grid, block, 0, stream>>>(pos_next, pos_curr, pos_prev,
                                             mass, elements, rest_vol,
                                             rest_inv, lam_p, mu_p,
                                             partials, V, E, Vblocks4,
                                             sI, sG, sS);
    reduce_kernel<<<1, 256, 0, stream>>>(partials, grid, out);
}